// Round 1
// baseline (202.340 us; speedup 1.0000x reference)
//
#include <hip/hip_runtime.h>

#define H 12
#define T 2048
#define HD 64
#define CEMB 768
#define M1 8192   // B*T
#define N1 2304   // 3*C
#define K1 768

typedef __attribute__((ext_vector_type(8))) short bf8;
typedef __attribute__((ext_vector_type(4))) float f4;
typedef __attribute__((ext_vector_type(16))) float f16v;
typedef __attribute__((ext_vector_type(4))) int i4;

__device__ __forceinline__ unsigned short f2bf(float f){
  union { float f; unsigned u; } v; v.f = f;
  unsigned r = v.u + 0x7FFFu + ((v.u >> 16) & 1u);
  return (unsigned short)(r >> 16);
}

__device__ __forceinline__ int cvtpk(float a, float b){
  int r;
  asm("v_cvt_pk_bf16_f32 %0, %1, %2" : "=v"(r) : "v"(a), "v"(b));
  return r;
}

// async global->LDS, 16B per lane; dest = wave-uniform base + lane*16
__device__ __forceinline__ void gload16(const unsigned short* g, unsigned short* l){
  __builtin_amdgcn_global_load_lds((const __attribute__((address_space(1))) void*)g,
                                   (__attribute__((address_space(3))) void*)l, 16, 0, 0);
}

__global__ __launch_bounds__(256) void cvt_f32_bf16(const float* __restrict__ in,
                                                    unsigned short* __restrict__ out, int n4){
  int i = blockIdx.x * blockDim.x + threadIdx.x;
  if (i < n4){
    float4 v = ((const float4*)in)[i];
    ushort4 o;
    o.x = f2bf(v.x); o.y = f2bf(v.y); o.z = f2bf(v.z); o.w = f2bf(v.w);
    ((ushort4*)out)[i] = o;
  }
}

// ---- QKV projection (m97-style). Q pre-scaled by 0.125*log2(e). V row-major. ----
__global__ __launch_bounds__(256) void gemm_qkv(const unsigned short* __restrict__ A,
                                                const unsigned short* __restrict__ Wb,
                                                const float* __restrict__ bias,
                                                unsigned short* __restrict__ Qb,
                                                unsigned short* __restrict__ Kb,
                                                unsigned short* __restrict__ Vr){
  __shared__ __align__(16) unsigned short As[128][64];
  __shared__ __align__(16) unsigned short Bs[128][64];
  int Lid = blockIdx.x + gridDim.x * blockIdx.y;      // 18*64 = 1152 = 8*144
  int L2 = (Lid & 7) * 144 + (Lid >> 3);
  const int m0 = (L2 / 18) * 128, n0 = (L2 % 18) * 128;
  const int tid = threadIdx.x, w = tid >> 6, lane = tid & 63;
  const int wm = (w >> 1) * 64, wn = (w & 1) * 64;
  const int l15 = lane & 15, g = lane >> 4;
  const int srow = lane >> 3;
  const int scol = ((lane & 7) ^ srow) * 8;
  f4 acc[4][4] = {};
  for (int k0 = 0; k0 < K1; k0 += 64){
    #pragma unroll
    for (int i = 0; i < 4; ++i){
      int rb = i * 32 + w * 8;
      gload16(&A [(size_t)(m0 + rb + srow) * K1 + k0 + scol], &As[rb][0]);
      gload16(&Wb[(size_t)(n0 + rb + srow) * K1 + k0 + scol], &Bs[rb][0]);
    }
    __syncthreads();
    #pragma unroll
    for (int kq = 0; kq < 2; ++kq){
      bf8 a[4], b[4];
      #pragma unroll
      for (int i = 0; i < 4; ++i){
        int row = wm + i * 16 + l15;
        a[i] = *(const bf8*)&As[row][(((kq << 2) + g) ^ (row & 7)) * 8];
      }
      #pragma unroll
      for (int j = 0; j < 4; ++j){
        int row = wn + j * 16 + l15;
        b[j] = *(const bf8*)&Bs[row][(((kq << 2) + g) ^ (row & 7)) * 8];
      }
      #pragma unroll
      for (int i = 0; i < 4; ++i)
        #pragma unroll
        for (int j = 0; j < 4; ++j)
          acc[i][j] = __builtin_amdgcn_mfma_f32_16x16x32_bf16(a[i], b[j], acc[i][j], 0, 0, 0);
    }
    __syncthreads();
  }
  #pragma unroll
  for (int j = 0; j < 4; ++j){
    int ncol = n0 + wn + j * 16 + l15;
    float bv = bias[ncol];
    int which = ncol / CEMB;
    int cc = ncol - which * CEMB;
    int h = cc >> 6, d = cc & 63;
    #pragma unroll
    for (int i = 0; i < 4; ++i){
      #pragma unroll
      for (int r = 0; r < 4; ++r){
        int m = m0 + wm + i * 16 + g * 4 + r;
        int b_ = m >> 11, t = m & 2047;
        size_t idx = ((size_t)(b_ * H + h) * T + t) * HD + d;
        float v = acc[i][j][r] + bv;
        if (which == 0)      Qb[idx] = f2bf(v * 0.18033688f);  // 0.125 * log2(e)
        else if (which == 1) Kb[idx] = f2bf(v);
        else                 Vr[idx] = f2bf(v);
      }
    }
  }
}

// ---- V transpose + kv-quad permute: Vr[bh][t][d] -> Vt[bh][d][perm(t)] ----
__global__ __launch_bounds__(256) void transpose_v(const unsigned short* __restrict__ Vr,
                                                   unsigned short* __restrict__ Vt){
  __shared__ unsigned short Lb[64][66];
  const int bh = blockIdx.y, tt = blockIdx.x;
  const unsigned short* src = Vr + ((size_t)bh * T + tt * 64) * HD;
  unsigned short* dst = Vt + (size_t)bh * HD * T + tt * 64;
  const int tid = threadIdx.x;
  {
    int r = tid >> 2, c = (tid & 3) * 16;
    uint4 v0 = *(const uint4*)&src[r * HD + c];
    uint4 v1 = *(const uint4*)&src[r * HD + c + 8];
    unsigned* lp = (unsigned*)&Lb[r][c];
    lp[0] = v0.x; lp[1] = v0.y; lp[2] = v0.z; lp[3] = v0.w;
    lp[4] = v1.x; lp[5] = v1.y; lp[6] = v1.z; lp[7] = v1.w;
  }
  __syncthreads();
  {
    int d = tid >> 2, tq = tid & 3;
    unsigned ov[8];
    #pragma unroll
    for (int jj = 0; jj < 8; ++jj){
      unsigned lo = Lb[tq * 16 + 2 * jj][d];
      unsigned hi = Lb[tq * 16 + 2 * jj + 1][d];
      ov[jj] = lo | (hi << 16);
    }
    uint4* op = (uint4*)&dst[(size_t)d * T + tq * 16];
    op[0] = make_uint4(ov[0], ov[1], ov[4], ov[5]);   // quads [0,2]
    op[1] = make_uint4(ov[2], ov[3], ov[6], ov[7]);   // quads [1,3]
  }
}

// ---- Flash causal attention v8: zero-LDS K/V path, register double-buffer ----
// K/V tiles were read from LDS exactly ONCE per wave (no intra-wave reuse), so
// LDS staging was a pure coalescing buffer costing 16.9KB/block (9-block LDS
// occupancy cap) + 6.4M bank-conflict cycles. Now each lane loads its MFMA
// fragments directly from global (16B aligned chunks, L2-resident) into named
// A/B register sets, prefetched one tile ahead. LDS shrinks to scb[32].
__device__ __forceinline__ void attn_stage(const unsigned short* __restrict__ Kp,
                                           const unsigned short* __restrict__ Vp,
                                           bf8 (&kf)[4], bf8 (&vf)[4],
                                           int kv0, int q31, int hi){
  #pragma unroll
  for (int ds = 0; ds < 4; ++ds)
    kf[ds] = *(const bf8*)&Kp[(size_t)(kv0 + q31) * HD + (2 * ds + hi) * 8];
  #pragma unroll
  for (int ks = 0; ks < 2; ++ks){
    vf[2 * ks]     = *(const bf8*)&Vp[(size_t)q31 * T        + kv0 + (2 * ks + hi) * 8];
    vf[2 * ks + 1] = *(const bf8*)&Vp[(size_t)(32 + q31) * T + kv0 + (2 * ks + hi) * 8];
  }
}

__device__ __forceinline__ void attn_tile(const bf8 (&kf)[4], const bf8 (&vf)[4],
                                          const bf8 (&qf)[4], f16v& o0, f16v& o1,
                                          float& m_i, float& l_i, float* scb,
                                          int kv0, bool diag, int q0, int q31, int hi){
  // ---- QK^T (swapped): s[kv][q]; K fragments straight from registers
  f16v s0 = {};
  __builtin_amdgcn_s_setprio(1);
  #pragma unroll
  for (int ds = 0; ds < 4; ++ds)
    s0 = __builtin_amdgcn_mfma_f32_32x32x16_bf16(kf[ds], qf[ds], s0, 0, 0, 0);
  __builtin_amdgcn_s_setprio(0);
  if (diag){    // diagonal tile: causal mask
    #pragma unroll
    for (int r = 0; r < 16; ++r){
      int kvr = kv0 + (r & 3) + 8 * (r >> 2) + 4 * hi;
      if (kvr > q0 + q31) s0[r] = -1e30f;
    }
  }
  // ---- row max (in-lane tree + one cross-hi exchange)
  float tm[16];
  #pragma unroll
  for (int r = 0; r < 16; ++r) tm[r] = s0[r];
  #pragma unroll
  for (int st = 8; st > 0; st >>= 1)
    #pragma unroll
    for (int r = 0; r < 8; ++r) if (r < st) tm[r] = fmaxf(tm[r], tm[r + st]);
  float mx = fmaxf(tm[0], __shfl_xor(tm[0], 32));
  // ---- defer-max: rescale only when max grew by > 8 (log2 domain)
  if (__any(mx > m_i + 8.f)){
    float mn = fmaxf(m_i, mx);
    float sc_ = __builtin_exp2f(m_i - mn);
    l_i *= sc_;
    scb[q31] = sc_;
    asm volatile("s_waitcnt lgkmcnt(0)" ::: "memory");
    __builtin_amdgcn_sched_barrier(0);
    #pragma unroll
    for (int j = 0; j < 4; ++j){
      float4 sq = *(const float4*)&scb[8 * j + 4 * hi];
      #pragma unroll
      for (int i = 0; i < 4; ++i){
        o0[4 * j + i] *= ((const float*)&sq)[i];
        o1[4 * j + i] *= ((const float*)&sq)[i];
      }
    }
    m_i = mn;
  }
  // ---- p = exp2(s - m) in place, row sum
  #pragma unroll
  for (int r = 0; r < 16; ++r) s0[r] = __builtin_exp2f(s0[r] - m_i);
  float ts[16];
  #pragma unroll
  for (int r = 0; r < 16; ++r) ts[r] = s0[r];
  #pragma unroll
  for (int st = 8; st > 0; st >>= 1)
    #pragma unroll
    for (int r = 0; r < 8; ++r) if (r < st) ts[r] += ts[r + st];
  l_i += ts[0] + __shfl_xor(ts[0], 32);
  // ---- PV: A = in-lane pack of own p regs; V^T fragments from registers
  union { i4 i; bf8 h; } pa;
  __builtin_amdgcn_s_setprio(1);
  #pragma unroll
  for (int ks = 0; ks < 2; ++ks){
    const int off = ks * 8;
    pa.i = (i4){ cvtpk(s0[off], s0[off+1]), cvtpk(s0[off+2], s0[off+3]),
                 cvtpk(s0[off+4], s0[off+5]), cvtpk(s0[off+6], s0[off+7]) };
    o0 = __builtin_amdgcn_mfma_f32_32x32x16_bf16(pa.h, vf[2 * ks],     o0, 0, 0, 0);
    o1 = __builtin_amdgcn_mfma_f32_32x32x16_bf16(pa.h, vf[2 * ks + 1], o1, 0, 0, 0);
  }
  __builtin_amdgcn_s_setprio(0);
}

__global__ __launch_bounds__(64, 3) void attn(const unsigned short* __restrict__ Qb,
                                              const unsigned short* __restrict__ Kb,
                                              const unsigned short* __restrict__ Vt,
                                              unsigned short* __restrict__ Yb){
  __shared__ float scb[32];
  const int bh = blockIdx.x;                 // 48 % 8 == 0 -> bh pinned to one XCD
  const int qidx = 63 - (int)blockIdx.y;     // LPT: heavy q-tiles dispatched first
  const int lane = threadIdx.x;
  const int q31 = lane & 31, hi = lane >> 5;
  const int q0 = qidx * 32;
  const unsigned short* Qp = Qb + (size_t)bh * T * HD;
  const unsigned short* Kp = Kb + (size_t)bh * T * HD;
  const unsigned short* Vp = Vt + (size_t)bh * HD * T;
  const int b_ = bh / H, h = bh % H;

  // Q fragments (B-operand): lane holds Q[q0+q31][ds*16 + hi*8 .. +8]
  bf8 qf[4];
  #pragma unroll
  for (int ds = 0; ds < 4; ++ds)
    qf[ds] = *(const bf8*)&Qp[(q0 + q31) * HD + ds * 16 + hi * 8];

  f16v o0 = {}, o1 = {};
  float m_i = -1e30f, l_i = 0.f;
  const int ntw = qidx + 1;

  // named register double-buffer (no runtime-indexed ext_vector arrays)
  bf8 kfA[4], vfA[4], kfB[4], vfB[4];
  attn_stage(Kp, Vp, kfA, vfA, 0, q31, hi);

  int t = 0;
  for (;;){
    if (t + 1 < ntw) attn_stage(Kp, Vp, kfB, vfB, (t + 1) * 32, q31, hi);
    attn_tile(kfA, vfA, qf, o0, o1, m_i, l_i, scb, t * 32, t == ntw - 1, q0, q31, hi);
    if (++t >= ntw) break;
    if (t + 1 < ntw) attn_stage(Kp, Vp, kfA, vfA, (t + 1) * 32, q31, hi);
    attn_tile(kfB, vfB, qf, o0, o1, m_i, l_i, scb, t * 32, t == ntw - 1, q0, q31, hi);
    if (++t >= ntw) break;
  }

  // ---- epilogue: redistribute 1/l across layouts, store Y (bf16)
  scb[q31] = 1.0f / l_i;
  asm volatile("s_waitcnt lgkmcnt(0)" ::: "memory");
  __builtin_amdgcn_sched_barrier(0);
  #pragma unroll
  for (int j = 0; j < 4; ++j){
    float4 sq = *(const float4*)&scb[8 * j + 4 * hi];
    #pragma unroll
    for (int i = 0; i < 4; ++i){
      int r = 4 * j + i;
      int qrow = q0 + (r & 3) + 8 * (r >> 2) + 4 * hi;
      float inv = ((const float*)&sq)[i];
      size_t base = ((size_t)b_ * T + qrow) * CEMB + h * HD;
      Yb[base + q31]      = f2bf(o0[r] * inv);
      Yb[base + 32 + q31] = f2bf(o1[r] * inv);
    }
  }
}

// ---- Output projection (m97 structure), fp32 out ----
__global__ __launch_bounds__(256) void gemm_out(const unsigned short* __restrict__ A,
                                                const unsigned short* __restrict__ Wb,
                                                const float* __restrict__ bias,
                                                float* __restrict__ out){
  __shared__ __align__(16) unsigned short As[128][64];
  __shared__ __align__(16) unsigned short Bs[128][64];
  int Lid = blockIdx.x + gridDim.x * blockIdx.y;      // 6*64 = 384 = 8*48
  int L2 = (Lid & 7) * 48 + (Lid >> 3);
  const int m0 = (L2 / 6) * 128, n0 = (L2 % 6) * 128;
  const int tid = threadIdx.x, w = tid >> 6, lane = tid & 63;
  const int wm = (w >> 1) * 64, wn = (w & 1) * 64;
  const int l15 = lane & 15, g = lane >> 4;
  const int srow = lane >> 3;
  const int scol = ((lane & 7) ^ srow) * 8;
  f4 acc[4][4] = {};
  for (int k0 = 0; k0 < CEMB; k0 += 64){
    #pragma unroll
    for (int i = 0; i < 4; ++i){
      int rb = i * 32 + w * 8;
      gload16(&A [(size_t)(m0 + rb + srow) * CEMB + k0 + scol], &As[rb][0]);
      gload16(&Wb[(size_t)(n0 + rb + srow) * CEMB + k0 + scol], &Bs[rb][0]);
    }
    __syncthreads();
    #pragma unroll
    for (int kq = 0; kq < 2; ++kq){
      bf8 a[4], b[4];
      #pragma unroll
      for (int i = 0; i < 4; ++i){
        int row = wm + i * 16 + l15;
        a[i] = *(const bf8*)&As[row][(((kq << 2) + g) ^ (row & 7)) * 8];
      }
      #pragma unroll
      for (int j = 0; j < 4; ++j){
        int row = wn + j * 16 + l15;
        b[j] = *(const bf8*)&Bs[row][(((kq << 2) + g) ^ (row & 7)) * 8];
      }
      #pragma unroll
      for (int i = 0; i < 4; ++i)
        #pragma unroll
        for (int j = 0; j < 4; ++j)
          acc[i][j] = __builtin_amdgcn_mfma_f32_16x16x32_bf16(a[i], b[j], acc[i][j], 0, 0, 0);
    }
    __syncthreads();
  }
  #pragma unroll
  for (int j = 0; j < 4; ++j){
    int ncol = n0 + wn + j * 16 + l15;
    float bv = bias[ncol];
    #pragma unroll
    for (int i = 0; i < 4; ++i){
      #pragma unroll
      for (int r = 0; r < 4; ++r){
        int m = m0 + wm + i * 16 + g * 4 + r;
        out[(size_t)m * CEMB + ncol] = acc[i][j][r] + bv;
      }
    }
  }
}

extern "C" void kernel_launch(void* const* d_in, const int* in_sizes, int n_in,
                              void* d_out, int out_size, void* d_ws, size_t ws_size,
                              hipStream_t stream){
  const float* x      = (const float*)d_in[0];
  const float* W_attn = (const float*)d_in[1];
  const float* b_attn = (const float*)d_in[2];
  const float* W_o    = (const float*)d_in[3];
  const float* b_o    = (const float*)d_in[4];
  float* out = (float*)d_out;

  char* ws = (char*)d_ws;
  const size_t SZ_T  = (size_t)48 * T * HD * 2;   // 12.58 MB (== X size)
  const size_t SZ_WA = (size_t)N1 * K1 * 2;
  const size_t SZ_WO = (size_t)CEMB * CEMB * 2;
  unsigned short* Xb = (unsigned short*)(ws);
  unsigned short* Vt = (unsigned short*)(ws);     // aliases Xb (dead after gemm_qkv)
  unsigned short* Wa = (unsigned short*)(ws + SZ_T);
  unsigned short* Wo = (unsigned short*)(ws + SZ_T + SZ_WA);
  unsigned short* Qb = (unsigned short*)(ws + SZ_T + SZ_WA + SZ_WO);
  unsigned short* Kb = (unsigned short*)(ws + SZ_T + SZ_WA + SZ_WO + SZ_T);
  unsigned short* Vr = (unsigned short*)(ws + SZ_T + SZ_WA + SZ_WO + 2 * SZ_T);
  unsigned short* Yb = Vr;                        // Vr dead after transpose_v

  cvt_f32_bf16<<<(M1 * K1 / 4 + 255) / 256, 256, 0, stream>>>(x, Xb, M1 * K1 / 4);
  cvt_f32_bf16<<<(N1 * K1 / 4 + 255) / 256, 256, 0, stream>>>(W_attn, Wa, N1 * K1 / 4);
  cvt_f32_bf16<<<(CEMB * CEMB / 4 + 255) / 256, 256, 0, stream>>>(W_o, Wo, CEMB * CEMB / 4);

  gemm_qkv<<<dim3(N1 / 128, M1 / 128), 256, 0, stream>>>(Xb, Wa, b_attn, Qb, Kb, Vr);
  transpose_v<<<dim3(T / 64, 48), 256, 0, stream>>>(Vr, Vt);
  attn<<<dim3(48, 64), 64, 0, stream>>>(Qb, Kb, Vt, Yb);
  gemm_out<<<dim3(CEMB / 128, M1 / 128), 256, 0, stream>>>(Yb, Wo, b_o, out);
}

// Round 2
// 176.163 us; speedup vs baseline: 1.1486x; 1.1486x over previous
//
#include <hip/hip_runtime.h>

#define H 12
#define T 2048
#define HD 64
#define CEMB 768
#define M1 8192   // B*T
#define N1 2304   // 3*C
#define K1 768

typedef __attribute__((ext_vector_type(8))) short bf8;
typedef __attribute__((ext_vector_type(4))) float f4;
typedef __attribute__((ext_vector_type(16))) float f16v;
typedef __attribute__((ext_vector_type(4))) int i4;

__device__ __forceinline__ unsigned short f2bf(float f){
  union { float f; unsigned u; } v; v.f = f;
  unsigned r = v.u + 0x7FFFu + ((v.u >> 16) & 1u);
  return (unsigned short)(r >> 16);
}

__device__ __forceinline__ int cvtpk(float a, float b){
  int r;
  asm("v_cvt_pk_bf16_f32 %0, %1, %2" : "=v"(r) : "v"(a), "v"(b));
  return r;
}

// async global->LDS, 16B per lane; dest = wave-uniform base + lane*16
__device__ __forceinline__ void gload16(const unsigned short* g, unsigned short* l){
  __builtin_amdgcn_global_load_lds((const __attribute__((address_space(1))) void*)g,
                                   (__attribute__((address_space(3))) void*)l, 16, 0, 0);
}

__global__ __launch_bounds__(256) void cvt_f32_bf16(const float* __restrict__ in,
                                                    unsigned short* __restrict__ out, int n4){
  int i = blockIdx.x * blockDim.x + threadIdx.x;
  if (i < n4){
    float4 v = ((const float4*)in)[i];
    ushort4 o;
    o.x = f2bf(v.x); o.y = f2bf(v.y); o.z = f2bf(v.z); o.w = f2bf(v.w);
    ((ushort4*)out)[i] = o;
  }
}

// ---- QKV projection (m97-style). Q pre-scaled by 0.125*log2(e). V row-major. ----
__global__ __launch_bounds__(256) void gemm_qkv(const unsigned short* __restrict__ A,
                                                const unsigned short* __restrict__ Wb,
                                                const float* __restrict__ bias,
                                                unsigned short* __restrict__ Qb,
                                                unsigned short* __restrict__ Kb,
                                                unsigned short* __restrict__ Vr){
  __shared__ __align__(16) unsigned short As[128][64];
  __shared__ __align__(16) unsigned short Bs[128][64];
  int Lid = blockIdx.x + gridDim.x * blockIdx.y;      // 18*64 = 1152 = 8*144
  int L2 = (Lid & 7) * 144 + (Lid >> 3);
  const int m0 = (L2 / 18) * 128, n0 = (L2 % 18) * 128;
  const int tid = threadIdx.x, w = tid >> 6, lane = tid & 63;
  const int wm = (w >> 1) * 64, wn = (w & 1) * 64;
  const int l15 = lane & 15, g = lane >> 4;
  const int srow = lane >> 3;
  const int scol = ((lane & 7) ^ srow) * 8;
  f4 acc[4][4] = {};
  for (int k0 = 0; k0 < K1; k0 += 64){
    #pragma unroll
    for (int i = 0; i < 4; ++i){
      int rb = i * 32 + w * 8;
      gload16(&A [(size_t)(m0 + rb + srow) * K1 + k0 + scol], &As[rb][0]);
      gload16(&Wb[(size_t)(n0 + rb + srow) * K1 + k0 + scol], &Bs[rb][0]);
    }
    __syncthreads();
    #pragma unroll
    for (int kq = 0; kq < 2; ++kq){
      bf8 a[4], b[4];
      #pragma unroll
      for (int i = 0; i < 4; ++i){
        int row = wm + i * 16 + l15;
        a[i] = *(const bf8*)&As[row][(((kq << 2) + g) ^ (row & 7)) * 8];
      }
      #pragma unroll
      for (int j = 0; j < 4; ++j){
        int row = wn + j * 16 + l15;
        b[j] = *(const bf8*)&Bs[row][(((kq << 2) + g) ^ (row & 7)) * 8];
      }
      #pragma unroll
      for (int i = 0; i < 4; ++i)
        #pragma unroll
        for (int j = 0; j < 4; ++j)
          acc[i][j] = __builtin_amdgcn_mfma_f32_16x16x32_bf16(a[i], b[j], acc[i][j], 0, 0, 0);
    }
    __syncthreads();
  }
  #pragma unroll
  for (int j = 0; j < 4; ++j){
    int ncol = n0 + wn + j * 16 + l15;
    float bv = bias[ncol];
    int which = ncol / CEMB;
    int cc = ncol - which * CEMB;
    int h = cc >> 6, d = cc & 63;
    #pragma unroll
    for (int i = 0; i < 4; ++i){
      #pragma unroll
      for (int r = 0; r < 4; ++r){
        int m = m0 + wm + i * 16 + g * 4 + r;
        int b_ = m >> 11, t = m & 2047;
        size_t idx = ((size_t)(b_ * H + h) * T + t) * HD + d;
        float v = acc[i][j][r] + bv;
        if (which == 0)      Qb[idx] = f2bf(v * 0.18033688f);  // 0.125 * log2(e)
        else if (which == 1) Kb[idx] = f2bf(v);
        else                 Vr[idx] = f2bf(v);
      }
    }
  }
}

// ---- V transpose + kv-quad permute: Vr[bh][t][d] -> Vt[bh][d][perm(t)] ----
__global__ __launch_bounds__(256) void transpose_v(const unsigned short* __restrict__ Vr,
                                                   unsigned short* __restrict__ Vt){
  __shared__ unsigned short Lb[64][66];
  const int bh = blockIdx.y, tt = blockIdx.x;
  const unsigned short* src = Vr + ((size_t)bh * T + tt * 64) * HD;
  unsigned short* dst = Vt + (size_t)bh * HD * T + tt * 64;
  const int tid = threadIdx.x;
  {
    int r = tid >> 2, c = (tid & 3) * 16;
    uint4 v0 = *(const uint4*)&src[r * HD + c];
    uint4 v1 = *(const uint4*)&src[r * HD + c + 8];
    unsigned* lp = (unsigned*)&Lb[r][c];
    lp[0] = v0.x; lp[1] = v0.y; lp[2] = v0.z; lp[3] = v0.w;
    lp[4] = v1.x; lp[5] = v1.y; lp[6] = v1.z; lp[7] = v1.w;
  }
  __syncthreads();
  {
    int d = tid >> 2, tq = tid & 3;
    unsigned ov[8];
    #pragma unroll
    for (int jj = 0; jj < 8; ++jj){
      unsigned lo = Lb[tq * 16 + 2 * jj][d];
      unsigned hi = Lb[tq * 16 + 2 * jj + 1][d];
      ov[jj] = lo | (hi << 16);
    }
    uint4* op = (uint4*)&dst[(size_t)d * T + tq * 16];
    op[0] = make_uint4(ov[0], ov[1], ov[4], ov[5]);   // quads [0,2]
    op[1] = make_uint4(ov[2], ov[3], ov[6], ov[7]);   // quads [1,3]
  }
}

// ---- Flash causal attention v9: v7 LDS-staged core + split-KV flash-decode ----
// v7 was latency/occupancy-bound (Occ 19%, both pipes low; grid = 3072 1-wave
// blocks with 1..64 tiles each). Split q-tiles with qidx>=32 into two waves
// (front/back half of the kv range) -> 4608 waves, max 32 tiles/wave, f32
// partials (m,l,O) merged by a tiny second kernel. V-tile LDS swizzle key
// changed (d&3 -> (d>>2)&3): read conflict 8-way -> 4-way (staging source
// pre-swizzle updated consistently; involution preserved).
__global__ __launch_bounds__(64) void attn(const unsigned short* __restrict__ Qb,
                                           const unsigned short* __restrict__ Kb,
                                           const unsigned short* __restrict__ Vt,
                                           unsigned short* __restrict__ Yb,
                                           float* __restrict__ P_O,
                                           float* __restrict__ P_ml){
  __shared__ __align__(16) unsigned short Ks[2][32][64];
  __shared__ __align__(16) unsigned short Vs[2][64][32];
  __shared__ float scb[32];
  const int bh = blockIdx.x;                 // 48 % 8 == 0 -> bh pinned to one XCD
  const int by = blockIdx.y;
  // job map (approx LPT): by 0..31 -> singles q=31-by (len 32..1);
  //                       by 32..95 -> splits q=63-((by-32)>>1), halves (len 32..16)
  int q, t0, t1, part;
  if (by < 32){ q = 31 - by; part = -1; t0 = 0; t1 = q + 1; }
  else {
    int i = (by - 32) >> 1; q = 63 - i; part = (by - 32) & 1;
    int n = q + 1, hh = n >> 1;
    t0 = part ? hh : 0; t1 = part ? n : hh;
  }
  const int lane = threadIdx.x;
  const int q31 = lane & 31, hi = lane >> 5;
  const int q0 = q * 32;
  const unsigned short* Qp = Qb + (size_t)bh * T * HD;
  const unsigned short* Kp = Kb + (size_t)bh * T * HD;
  const unsigned short* Vp = Vt + (size_t)bh * HD * T;
  const int b_ = bh / H, h = bh % H;

  // staging lane constants (pre-swizzled source chunks; LDS dest is linear)
  const int krow = lane >> 3;                         // 0..7 within 8-row slab
  const int kcs  = ((lane & 7) ^ krow) * 8;           // K: chunk ^ (row&7)
  const int vrow = lane >> 2;                         // 0..15 within 16-row slab
  const int vcs  = ((lane & 3) ^ ((lane >> 4) & 3)) * 8;  // V: chunk ^ ((d>>2)&3)

  // Q fragments (B-operand): lane holds Q[q0+q31][ds*16 + hi*8 .. +8]
  bf8 qf[4];
  #pragma unroll
  for (int ds = 0; ds < 4; ++ds)
    qf[ds] = *(const bf8*)&Qp[(q0 + q31) * HD + ds * 16 + hi * 8];

  f16v o0 = {}, o1 = {};
  float m_i = -1e30f, l_i = 0.f;

  // prologue: stage tile t0 into buf 0
  {
    const int kv0 = t0 * 32;
    #pragma unroll
    for (int it = 0; it < 4; ++it)
      gload16(&Kp[(size_t)(kv0 + it * 8 + krow) * HD + kcs], &Ks[0][it * 8][0]);
    #pragma unroll
    for (int it = 0; it < 4; ++it)
      gload16(&Vp[(size_t)(it * 16 + vrow) * T + kv0 + vcs], &Vs[0][it * 16][0]);
  }

  #pragma unroll 2
  for (int t = t0; t < t1; ++t){
    const int cur = (t - t0) & 1;
    const int kv0 = t * 32;
    if (t + 1 < t1){     // stage next tile into other buffer, then counted wait
      const int nkv = kv0 + 32;
      #pragma unroll
      for (int it = 0; it < 4; ++it)
        gload16(&Kp[(size_t)(nkv + it * 8 + krow) * HD + kcs], &Ks[cur ^ 1][it * 8][0]);
      #pragma unroll
      for (int it = 0; it < 4; ++it)
        gload16(&Vp[(size_t)(it * 16 + vrow) * T + nkv + vcs], &Vs[cur ^ 1][it * 16][0]);
      asm volatile("s_waitcnt vmcnt(8)" ::: "memory");
    } else {
      asm volatile("s_waitcnt vmcnt(0)" ::: "memory");
    }
    __builtin_amdgcn_sched_barrier(0);

    // ---- QK^T (swapped): s[kv][q]; K from LDS (XOR-swizzled read)
    f16v s0 = {};
    __builtin_amdgcn_s_setprio(1);
    #pragma unroll
    for (int ds = 0; ds < 4; ++ds){
      bf8 k0 = *(const bf8*)&Ks[cur][q31][(((2 * ds + hi)) ^ (q31 & 7)) * 8];
      s0 = __builtin_amdgcn_mfma_f32_32x32x16_bf16(k0, qf[ds], s0, 0, 0, 0);
    }
    __builtin_amdgcn_s_setprio(0);
    if (t == q){          // diagonal tile: causal mask
      #pragma unroll
      for (int r = 0; r < 16; ++r){
        int kvr = kv0 + (r & 3) + 8 * (r >> 2) + 4 * hi;
        if (kvr > q0 + q31) s0[r] = -1e30f;
      }
    }
    // ---- row max (in-lane tree + one cross-hi exchange)
    float tm[16];
    #pragma unroll
    for (int r = 0; r < 16; ++r) tm[r] = s0[r];
    #pragma unroll
    for (int st = 8; st > 0; st >>= 1)
      #pragma unroll
      for (int r = 0; r < 8; ++r) if (r < st) tm[r] = fmaxf(tm[r], tm[r + st]);
    float mx = fmaxf(tm[0], __shfl_xor(tm[0], 32));
    // ---- defer-max: rescale only when max grew by > 8 (log2 domain)
    if (__any(mx > m_i + 8.f)){
      float mn = fmaxf(m_i, mx);
      float sc_ = __builtin_exp2f(m_i - mn);
      l_i *= sc_;
      scb[q31] = sc_;
      asm volatile("s_waitcnt lgkmcnt(0)" ::: "memory");
      __builtin_amdgcn_sched_barrier(0);
      #pragma unroll
      for (int j = 0; j < 4; ++j){
        float4 sq = *(const float4*)&scb[8 * j + 4 * hi];
        #pragma unroll
        for (int i = 0; i < 4; ++i){
          o0[4 * j + i] *= ((const float*)&sq)[i];
          o1[4 * j + i] *= ((const float*)&sq)[i];
        }
      }
      m_i = mn;
    }
    // ---- p = exp2(s - m) in place, row sum
    #pragma unroll
    for (int r = 0; r < 16; ++r) s0[r] = __builtin_exp2f(s0[r] - m_i);
    float ts[16];
    #pragma unroll
    for (int r = 0; r < 16; ++r) ts[r] = s0[r];
    #pragma unroll
    for (int st = 8; st > 0; st >>= 1)
      #pragma unroll
      for (int r = 0; r < 8; ++r) if (r < st) ts[r] += ts[r + st];
    l_i += ts[0] + __shfl_xor(ts[0], 32);
    // ---- PV: A = in-lane pack of own p regs; V^T from LDS (quad-permuted)
    union { i4 i; bf8 h; } pa;
    __builtin_amdgcn_s_setprio(1);
    #pragma unroll
    for (int ks = 0; ks < 2; ++ks){
      const int off = ks * 8;
      pa.i = (i4){ cvtpk(s0[off], s0[off+1]), cvtpk(s0[off+2], s0[off+3]),
                   cvtpk(s0[off+4], s0[off+5]), cvtpk(s0[off+6], s0[off+7]) };
      bf8 v0 = *(const bf8*)&Vs[cur][q31]     [((2 * ks + hi) ^ ((q31 >> 2) & 3)) * 8];
      bf8 v1 = *(const bf8*)&Vs[cur][32 + q31][((2 * ks + hi) ^ ((q31 >> 2) & 3)) * 8];
      o0 = __builtin_amdgcn_mfma_f32_32x32x16_bf16(pa.h, v0, o0, 0, 0, 0);
      o1 = __builtin_amdgcn_mfma_f32_32x32x16_bf16(pa.h, v1, o1, 0, 0, 0);
    }
    __builtin_amdgcn_s_setprio(0);
  }

  if (part < 0){
    // ---- epilogue: redistribute 1/l across layouts, store Y (bf16)
    scb[q31] = 1.0f / l_i;
    asm volatile("s_waitcnt lgkmcnt(0)" ::: "memory");
    __builtin_amdgcn_sched_barrier(0);
    #pragma unroll
    for (int j = 0; j < 4; ++j){
      float4 sq = *(const float4*)&scb[8 * j + 4 * hi];
      #pragma unroll
      for (int i = 0; i < 4; ++i){
        int r = 4 * j + i;
        int qrow = q0 + (r & 3) + 8 * (r >> 2) + 4 * hi;
        float inv = ((const float*)&sq)[i];
        size_t base = ((size_t)b_ * T + qrow) * CEMB + h * HD;
        Yb[base + q31]      = f2bf(o0[r] * inv);
        Yb[base + 32 + q31] = f2bf(o1[r] * inv);
      }
    }
  } else {
    // ---- partial epilogue: unnormalized O + (m,l) to workspace (f32)
    const int qt = q - 32;
    float* Pml = P_ml + (((size_t)(bh * 32 + qt) * 2 + part) * 2) * 32;
    if (hi == 0){ Pml[q31] = m_i; Pml[32 + q31] = l_i; }
    float* Po = P_O + (((size_t)(bh * 32 + qt) * 2 + part) * 32) * 64;
    #pragma unroll
    for (int r = 0; r < 16; ++r){
      int row = (r & 3) + 8 * (r >> 2) + 4 * hi;
      Po[row * 64 + q31]      = o0[r];
      Po[row * 64 + 32 + q31] = o1[r];
    }
  }
}

// ---- merge two kv-half partials for q-tiles 32..63 ----
__global__ __launch_bounds__(256) void merge_attn(const float* __restrict__ P_O,
                                                  const float* __restrict__ P_ml,
                                                  unsigned short* __restrict__ Yb){
  const int bh = blockIdx.y, qt = blockIdx.x;      // q = 32+qt
  const int b_ = bh / H, h = bh % H;
  const int tid = threadIdx.x;
  const int row = tid >> 3, d0 = (tid & 7) * 8;
  const size_t basml = ((size_t)(bh * 32 + qt) * 2) * 2 * 32;
  float m0 = P_ml[basml + row];
  float l0 = P_ml[basml + 32 + row];
  float m1 = P_ml[basml + 64 + row];
  float l1 = P_ml[basml + 96 + row];
  float M = fmaxf(m0, m1);
  float w0 = __builtin_exp2f(m0 - M), w1 = __builtin_exp2f(m1 - M);
  float inv = 1.0f / (l0 * w0 + l1 * w1);
  const size_t baso = ((size_t)(bh * 32 + qt) * 2) * 32 * 64;
  const float* O0 = P_O + baso + row * 64 + d0;
  const float* O1 = P_O + baso + 2048 + row * 64 + d0;
  int qrow = (32 + qt) * 32 + row;
  unsigned short* Y = Yb + ((size_t)b_ * T + qrow) * CEMB + h * HD + d0;
  #pragma unroll
  for (int j = 0; j < 2; ++j){
    float4 a = *(const float4*)&O0[4 * j];
    float4 b = *(const float4*)&O1[4 * j];
    ushort4 o;
    o.x = f2bf((a.x * w0 + b.x * w1) * inv);
    o.y = f2bf((a.y * w0 + b.y * w1) * inv);
    o.z = f2bf((a.z * w0 + b.z * w1) * inv);
    o.w = f2bf((a.w * w0 + b.w * w1) * inv);
    ((ushort4*)Y)[j] = o;
  }
}

// ---- Output projection (m97 structure), fp32 out ----
__global__ __launch_bounds__(256) void gemm_out(const unsigned short* __restrict__ A,
                                                const unsigned short* __restrict__ Wb,
                                                const float* __restrict__ bias,
                                                float* __restrict__ out){
  __shared__ __align__(16) unsigned short As[128][64];
  __shared__ __align__(16) unsigned short Bs[128][64];
  int Lid = blockIdx.x + gridDim.x * blockIdx.y;      // 6*64 = 384 = 8*48
  int L2 = (Lid & 7) * 48 + (Lid >> 3);
  const int m0 = (L2 / 6) * 128, n0 = (L2 % 6) * 128;
  const int tid = threadIdx.x, w = tid >> 6, lane = tid & 63;
  const int wm = (w >> 1) * 64, wn = (w & 1) * 64;
  const int l15 = lane & 15, g = lane >> 4;
  const int srow = lane >> 3;
  const int scol = ((lane & 7) ^ srow) * 8;
  f4 acc[4][4] = {};
  for (int k0 = 0; k0 < CEMB; k0 += 64){
    #pragma unroll
    for (int i = 0; i < 4; ++i){
      int rb = i * 32 + w * 8;
      gload16(&A [(size_t)(m0 + rb + srow) * CEMB + k0 + scol], &As[rb][0]);
      gload16(&Wb[(size_t)(n0 + rb + srow) * CEMB + k0 + scol], &Bs[rb][0]);
    }
    __syncthreads();
    #pragma unroll
    for (int kq = 0; kq < 2; ++kq){
      bf8 a[4], b[4];
      #pragma unroll
      for (int i = 0; i < 4; ++i){
        int row = wm + i * 16 + l15;
        a[i] = *(const bf8*)&As[row][(((kq << 2) + g) ^ (row & 7)) * 8];
      }
      #pragma unroll
      for (int j = 0; j < 4; ++j){
        int row = wn + j * 16 + l15;
        b[j] = *(const bf8*)&Bs[row][(((kq << 2) + g) ^ (row & 7)) * 8];
      }
      #pragma unroll
      for (int i = 0; i < 4; ++i)
        #pragma unroll
        for (int j = 0; j < 4; ++j)
          acc[i][j] = __builtin_amdgcn_mfma_f32_16x16x32_bf16(a[i], b[j], acc[i][j], 0, 0, 0);
    }
    __syncthreads();
  }
  #pragma unroll
  for (int j = 0; j < 4; ++j){
    int ncol = n0 + wn + j * 16 + l15;
    float bv = bias[ncol];
    #pragma unroll
    for (int i = 0; i < 4; ++i){
      #pragma unroll
      for (int r = 0; r < 4; ++r){
        int m = m0 + wm + i * 16 + g * 4 + r;
        out[(size_t)m * CEMB + ncol] = acc[i][j][r] + bv;
      }
    }
  }
}

extern "C" void kernel_launch(void* const* d_in, const int* in_sizes, int n_in,
                              void* d_out, int out_size, void* d_ws, size_t ws_size,
                              hipStream_t stream){
  const float* x      = (const float*)d_in[0];
  const float* W_attn = (const float*)d_in[1];
  const float* b_attn = (const float*)d_in[2];
  const float* W_o    = (const float*)d_in[3];
  const float* b_o    = (const float*)d_in[4];
  float* out = (float*)d_out;

  char* ws = (char*)d_ws;
  const size_t SZ_T  = (size_t)48 * T * HD * 2;   // 12.58 MB (== X size)
  const size_t SZ_WA = (size_t)N1 * K1 * 2;
  const size_t SZ_WO = (size_t)CEMB * CEMB * 2;
  unsigned short* Xb = (unsigned short*)(ws);
  unsigned short* Vt = (unsigned short*)(ws);     // aliases Xb (dead after gemm_qkv)
  unsigned short* Wa = (unsigned short*)(ws + SZ_T);
  unsigned short* Wo = (unsigned short*)(ws + SZ_T + SZ_WA);
  unsigned short* Qb = (unsigned short*)(ws + SZ_T + SZ_WA + SZ_WO);
  unsigned short* Kb = (unsigned short*)(ws + SZ_T + SZ_WA + SZ_WO + SZ_T);
  unsigned short* Vr = (unsigned short*)(ws + SZ_T + SZ_WA + SZ_WO + 2 * SZ_T);
  unsigned short* Yb = Vr;                        // Vr dead after transpose_v
  const size_t off_p = 4 * SZ_T + SZ_WA + SZ_WO;  // end of existing layout
  const size_t SZ_PO = (size_t)48 * 32 * 2 * 32 * 64 * 4;   // 25.2 MB
  float* P_O  = (float*)(ws + off_p);
  float* P_ml = (float*)(ws + off_p + SZ_PO);

  cvt_f32_bf16<<<(M1 * K1 / 4 + 255) / 256, 256, 0, stream>>>(x, Xb, M1 * K1 / 4);
  cvt_f32_bf16<<<(N1 * K1 / 4 + 255) / 256, 256, 0, stream>>>(W_attn, Wa, N1 * K1 / 4);
  cvt_f32_bf16<<<(CEMB * CEMB / 4 + 255) / 256, 256, 0, stream>>>(W_o, Wo, CEMB * CEMB / 4);

  gemm_qkv<<<dim3(N1 / 128, M1 / 128), 256, 0, stream>>>(Xb, Wa, b_attn, Qb, Kb, Vr);
  transpose_v<<<dim3(T / 64, 48), 256, 0, stream>>>(Vr, Vt);
  attn<<<dim3(48, 96), 64, 0, stream>>>(Qb, Kb, Vt, Yb, P_O, P_ml);
  merge_attn<<<dim3(32, 48), 256, 0, stream>>>(P_O, P_ml, Yb);
  gemm_out<<<dim3(CEMB / 128, M1 / 128), 256, 0, stream>>>(Yb, Wo, b_o, out);
}

// Round 4
// 173.598 us; speedup vs baseline: 1.1656x; 1.0148x over previous
//
#include <hip/hip_runtime.h>

#define H 12
#define T 2048
#define HD 64
#define CEMB 768
#define M1 8192   // B*T
#define N1 2304   // 3*C
#define K1 768

typedef __attribute__((ext_vector_type(8))) short bf8;
typedef __attribute__((ext_vector_type(4))) float f4;
typedef __attribute__((ext_vector_type(16))) float f16v;
typedef __attribute__((ext_vector_type(4))) int i4;

__device__ __forceinline__ unsigned short f2bf(float f){
  union { float f; unsigned u; } v; v.f = f;
  unsigned r = v.u + 0x7FFFu + ((v.u >> 16) & 1u);
  return (unsigned short)(r >> 16);
}

__device__ __forceinline__ int cvtpk(float a, float b){
  int r;
  asm("v_cvt_pk_bf16_f32 %0, %1, %2" : "=v"(r) : "v"(a), "v"(b));
  return r;
}

// async global->LDS, 16B per lane; dest = wave-uniform base + lane*16
__device__ __forceinline__ void gload16(const unsigned short* g, unsigned short* l){
  __builtin_amdgcn_global_load_lds((const __attribute__((address_space(1))) void*)g,
                                   (__attribute__((address_space(3))) void*)l, 16, 0, 0);
}

__global__ __launch_bounds__(256) void cvt_f32_bf16(const float* __restrict__ in,
                                                    unsigned short* __restrict__ out, int n4){
  int i = blockIdx.x * blockDim.x + threadIdx.x;
  if (i < n4){
    float4 v = ((const float4*)in)[i];
    ushort4 o;
    o.x = f2bf(v.x); o.y = f2bf(v.y); o.z = f2bf(v.z); o.w = f2bf(v.w);
    ((ushort4*)out)[i] = o;
  }
}

// ---- QKV projection (m97-style). Q pre-scaled by 0.125*log2(e). V row-major. ----
__global__ __launch_bounds__(256) void gemm_qkv(const unsigned short* __restrict__ A,
                                                const unsigned short* __restrict__ Wb,
                                                const float* __restrict__ bias,
                                                unsigned short* __restrict__ Qb,
                                                unsigned short* __restrict__ Kb,
                                                unsigned short* __restrict__ Vr){
  __shared__ __align__(16) unsigned short As[128][64];
  __shared__ __align__(16) unsigned short Bs[128][64];
  int Lid = blockIdx.x + gridDim.x * blockIdx.y;      // 18*64 = 1152 = 8*144
  int L2 = (Lid & 7) * 144 + (Lid >> 3);
  const int m0 = (L2 / 18) * 128, n0 = (L2 % 18) * 128;
  const int tid = threadIdx.x, w = tid >> 6, lane = tid & 63;
  const int wm = (w >> 1) * 64, wn = (w & 1) * 64;
  const int l15 = lane & 15, g = lane >> 4;
  const int srow = lane >> 3;
  const int scol = ((lane & 7) ^ srow) * 8;
  f4 acc[4][4] = {};
  for (int k0 = 0; k0 < K1; k0 += 64){
    #pragma unroll
    for (int i = 0; i < 4; ++i){
      int rb = i * 32 + w * 8;
      gload16(&A [(size_t)(m0 + rb + srow) * K1 + k0 + scol], &As[rb][0]);
      gload16(&Wb[(size_t)(n0 + rb + srow) * K1 + k0 + scol], &Bs[rb][0]);
    }
    __syncthreads();
    #pragma unroll
    for (int kq = 0; kq < 2; ++kq){
      bf8 a[4], b[4];
      #pragma unroll
      for (int i = 0; i < 4; ++i){
        int row = wm + i * 16 + l15;
        a[i] = *(const bf8*)&As[row][(((kq << 2) + g) ^ (row & 7)) * 8];
      }
      #pragma unroll
      for (int j = 0; j < 4; ++j){
        int row = wn + j * 16 + l15;
        b[j] = *(const bf8*)&Bs[row][(((kq << 2) + g) ^ (row & 7)) * 8];
      }
      #pragma unroll
      for (int i = 0; i < 4; ++i)
        #pragma unroll
        for (int j = 0; j < 4; ++j)
          acc[i][j] = __builtin_amdgcn_mfma_f32_16x16x32_bf16(a[i], b[j], acc[i][j], 0, 0, 0);
    }
    __syncthreads();
  }
  #pragma unroll
  for (int j = 0; j < 4; ++j){
    int ncol = n0 + wn + j * 16 + l15;
    float bv = bias[ncol];
    int which = ncol / CEMB;
    int cc = ncol - which * CEMB;
    int h = cc >> 6, d = cc & 63;
    #pragma unroll
    for (int i = 0; i < 4; ++i){
      #pragma unroll
      for (int r = 0; r < 4; ++r){
        int m = m0 + wm + i * 16 + g * 4 + r;
        int b_ = m >> 11, t = m & 2047;
        size_t idx = ((size_t)(b_ * H + h) * T + t) * HD + d;
        float v = acc[i][j][r] + bv;
        if (which == 0)      Qb[idx] = f2bf(v * 0.18033688f);  // 0.125 * log2(e)
        else if (which == 1) Kb[idx] = f2bf(v);
        else                 Vr[idx] = f2bf(v);
      }
    }
  }
}

// ---- V transpose + kv-quad permute: Vr[bh][t][d] -> Vt[bh][d][perm(t)] ----
__global__ __launch_bounds__(256) void transpose_v(const unsigned short* __restrict__ Vr,
                                                   unsigned short* __restrict__ Vt){
  __shared__ unsigned short Lb[64][66];
  const int bh = blockIdx.y, tt = blockIdx.x;
  const unsigned short* src = Vr + ((size_t)bh * T + tt * 64) * HD;
  unsigned short* dst = Vt + (size_t)bh * HD * T + tt * 64;
  const int tid = threadIdx.x;
  {
    int r = tid >> 2, c = (tid & 3) * 16;
    uint4 v0 = *(const uint4*)&src[r * HD + c];
    uint4 v1 = *(const uint4*)&src[r * HD + c + 8];
    unsigned* lp = (unsigned*)&Lb[r][c];
    lp[0] = v0.x; lp[1] = v0.y; lp[2] = v0.z; lp[3] = v0.w;
    lp[4] = v1.x; lp[5] = v1.y; lp[6] = v1.z; lp[7] = v1.w;
  }
  __syncthreads();
  {
    int d = tid >> 2, tq = tid & 3;
    unsigned ov[8];
    #pragma unroll
    for (int jj = 0; jj < 8; ++jj){
      unsigned lo = Lb[tq * 16 + 2 * jj][d];
      unsigned hi = Lb[tq * 16 + 2 * jj + 1][d];
      ov[jj] = lo | (hi << 16);
    }
    uint4* op = (uint4*)&dst[(size_t)d * T + tq * 16];
    op[0] = make_uint4(ov[0], ov[1], ov[4], ov[5]);   // quads [0,2]
    op[1] = make_uint4(ov[2], ov[3], ov[6], ov[7]);   // quads [1,3]
  }
}

// ---- Flash causal attention v11: v7 max-tracked numerics + matrix-pipe row-sum ----
// Softmax numerics restored to the proven v7 form (running max + defer-max,
// p = exp2(s - m) with p in (0,256]). The f32 sum tree + scb round-trips are
// replaced by an all-ones B-operand MFMA accumulating row sums in ol (same
// bf16-rounded P as the PV numerator, so rounding bias cancels in the ratio).
// Defer-max rescale also scales ol; scale redistribution via __shfl (no LDS).
// Epilogue: exact 1.0f/ol[r] per register. scb deleted -> LDS exactly 16 KiB
// -> 10 blocks/CU. V-tile swizzle keyed on (d>>2)&3 (4-way, from R2).
__global__ __launch_bounds__(64) void attn(const unsigned short* __restrict__ Qb,
                                           const unsigned short* __restrict__ Kb,
                                           const unsigned short* __restrict__ Vt,
                                           unsigned short* __restrict__ Yb){
  __shared__ __align__(16) unsigned short Ks[2][32][64];
  __shared__ __align__(16) unsigned short Vs[2][64][32];
  const int bh = blockIdx.x;                 // 48 % 8 == 0 -> bh pinned to one XCD
  const int qidx = 63 - (int)blockIdx.y;     // LPT: heavy q-tiles dispatched first
  const int lane = threadIdx.x;
  const int q31 = lane & 31, hi = lane >> 5;
  const int q0 = qidx * 32;
  const unsigned short* Qp = Qb + (size_t)bh * T * HD;
  const unsigned short* Kp = Kb + (size_t)bh * T * HD;
  const unsigned short* Vp = Vt + (size_t)bh * HD * T;
  const int b_ = bh / H, h = bh % H;

  // staging lane constants (pre-swizzled source chunks; LDS dest is linear)
  const int krow = lane >> 3;                         // 0..7 within 8-row slab
  const int kcs  = ((lane & 7) ^ krow) * 8;           // K: chunk ^ (row&7)
  const int vrow = lane >> 2;                         // 0..15 within 16-row slab
  const int vcs  = ((lane & 3) ^ ((lane >> 4) & 3)) * 8;  // V: chunk ^ ((d>>2)&3)

  // Q fragments (B-operand): lane holds Q[q0+q31][ds*16 + hi*8 .. +8]
  bf8 qf[4];
  #pragma unroll
  for (int ds = 0; ds < 4; ++ds)
    qf[ds] = *(const bf8*)&Qp[(q0 + q31) * HD + ds * 16 + hi * 8];

  // all-ones bf16 B operand for the row-sum MFMA
  bf8 ones;
  #pragma unroll
  for (int j = 0; j < 8; ++j) ones[j] = (short)0x3F80;

  f16v o0 = {}, o1 = {}, ol = {};
  float m_i = -1e30f;
  const int ntw = qidx + 1;

  // prologue: stage tile 0 into buf 0
  #pragma unroll
  for (int it = 0; it < 4; ++it)
    gload16(&Kp[(size_t)(it * 8 + krow) * HD + kcs], &Ks[0][it * 8][0]);
  #pragma unroll
  for (int it = 0; it < 4; ++it)
    gload16(&Vp[(size_t)(it * 16 + vrow) * T + vcs], &Vs[0][it * 16][0]);

  #pragma unroll 2
  for (int t = 0; t < ntw; ++t){
    const int cur = t & 1;
    const int kv0 = t * 32;
    if (t + 1 < ntw){     // stage next tile into other buffer, then counted wait
      const int nkv = kv0 + 32;
      #pragma unroll
      for (int it = 0; it < 4; ++it)
        gload16(&Kp[(size_t)(nkv + it * 8 + krow) * HD + kcs], &Ks[cur ^ 1][it * 8][0]);
      #pragma unroll
      for (int it = 0; it < 4; ++it)
        gload16(&Vp[(size_t)(it * 16 + vrow) * T + nkv + vcs], &Vs[cur ^ 1][it * 16][0]);
      asm volatile("s_waitcnt vmcnt(8)" ::: "memory");
    } else {
      asm volatile("s_waitcnt vmcnt(0)" ::: "memory");
    }
    __builtin_amdgcn_sched_barrier(0);

    // ---- QK^T (swapped): s[kv][q]; K from LDS (XOR-swizzled read)
    f16v s0 = {};
    __builtin_amdgcn_s_setprio(1);
    #pragma unroll
    for (int ds = 0; ds < 4; ++ds){
      bf8 k0 = *(const bf8*)&Ks[cur][q31][(((2 * ds + hi)) ^ (q31 & 7)) * 8];
      s0 = __builtin_amdgcn_mfma_f32_32x32x16_bf16(k0, qf[ds], s0, 0, 0, 0);
    }
    __builtin_amdgcn_s_setprio(0);
    if (t == ntw - 1){    // diagonal tile: causal mask
      #pragma unroll
      for (int r = 0; r < 16; ++r){
        int kvr = kv0 + (r & 3) + 8 * (r >> 2) + 4 * hi;
        if (kvr > q0 + q31) s0[r] = -1e30f;
      }
    }
    // ---- row max (in-lane tree + one cross-hi exchange)
    float tm[16];
    #pragma unroll
    for (int r = 0; r < 16; ++r) tm[r] = s0[r];
    #pragma unroll
    for (int st = 8; st > 0; st >>= 1)
      #pragma unroll
      for (int r = 0; r < 8; ++r) if (r < st) tm[r] = fmaxf(tm[r], tm[r + st]);
    float mx = fmaxf(tm[0], __shfl_xor(tm[0], 32));
    // ---- defer-max: rescale only when max grew by > 8 (log2 domain);
    //      scale redistributed via shfl (row f(r,hi) held by lane q31==row)
    if (__any(mx > m_i + 8.f)){
      float mn = fmaxf(m_i, mx);
      float sc_ = __builtin_exp2f(m_i - mn);
      #pragma unroll
      for (int r = 0; r < 16; ++r){
        float s = __shfl(sc_, (r & 3) + 8 * (r >> 2) + 4 * hi);
        o0[r] *= s; o1[r] *= s; ol[r] *= s;
      }
      m_i = mn;
    }
    // ---- p = exp2(s - m) in place
    #pragma unroll
    for (int r = 0; r < 16; ++r) s0[r] = __builtin_exp2f(s0[r] - m_i);
    // ---- PV + row-sum: A = in-lane pack of own p regs; V^T from LDS;
    //      l accumulated by all-ones MFMA on the matrix pipe
    union { i4 i; bf8 h; } pa;
    __builtin_amdgcn_s_setprio(1);
    #pragma unroll
    for (int ks = 0; ks < 2; ++ks){
      const int off = ks * 8;
      pa.i = (i4){ cvtpk(s0[off], s0[off+1]), cvtpk(s0[off+2], s0[off+3]),
                   cvtpk(s0[off+4], s0[off+5]), cvtpk(s0[off+6], s0[off+7]) };
      bf8 v0 = *(const bf8*)&Vs[cur][q31]     [((2 * ks + hi) ^ ((q31 >> 2) & 3)) * 8];
      bf8 v1 = *(const bf8*)&Vs[cur][32 + q31][((2 * ks + hi) ^ ((q31 >> 2) & 3)) * 8];
      o0 = __builtin_amdgcn_mfma_f32_32x32x16_bf16(pa.h, v0, o0, 0, 0, 0);
      o1 = __builtin_amdgcn_mfma_f32_32x32x16_bf16(pa.h, v1, o1, 0, 0, 0);
      ol = __builtin_amdgcn_mfma_f32_32x32x16_bf16(pa.h, ones, ol, 0, 0, 0);
    }
    __builtin_amdgcn_s_setprio(0);
  }

  // ---- epilogue: per-register exact 1/l, store Y (bf16); no LDS, no cross-lane
  #pragma unroll
  for (int r = 0; r < 16; ++r){
    int qrow = q0 + (r & 3) + 8 * (r >> 2) + 4 * hi;
    float inv = 1.0f / ol[r];
    size_t base = ((size_t)b_ * T + qrow) * CEMB + h * HD;
    Yb[base + q31]      = f2bf(o0[r] * inv);
    Yb[base + 32 + q31] = f2bf(o1[r] * inv);
  }
}

// ---- Output projection (m97 structure), fp32 out ----
__global__ __launch_bounds__(256) void gemm_out(const unsigned short* __restrict__ A,
                                                const unsigned short* __restrict__ Wb,
                                                const float* __restrict__ bias,
                                                float* __restrict__ out){
  __shared__ __align__(16) unsigned short As[128][64];
  __shared__ __align__(16) unsigned short Bs[128][64];
  int Lid = blockIdx.x + gridDim.x * blockIdx.y;      // 6*64 = 384 = 8*48
  int L2 = (Lid & 7) * 48 + (Lid >> 3);
  const int m0 = (L2 / 6) * 128, n0 = (L2 % 6) * 128;
  const int tid = threadIdx.x, w = tid >> 6, lane = tid & 63;
  const int wm = (w >> 1) * 64, wn = (w & 1) * 64;
  const int l15 = lane & 15, g = lane >> 4;
  const int srow = lane >> 3;
  const int scol = ((lane & 7) ^ srow) * 8;
  f4 acc[4][4] = {};
  for (int k0 = 0; k0 < CEMB; k0 += 64){
    #pragma unroll
    for (int i = 0; i < 4; ++i){
      int rb = i * 32 + w * 8;
      gload16(&A [(size_t)(m0 + rb + srow) * CEMB + k0 + scol], &As[rb][0]);
      gload16(&Wb[(size_t)(n0 + rb + srow) * CEMB + k0 + scol], &Bs[rb][0]);
    }
    __syncthreads();
    #pragma unroll
    for (int kq = 0; kq < 2; ++kq){
      bf8 a[4], b[4];
      #pragma unroll
      for (int i = 0; i < 4; ++i){
        int row = wm + i * 16 + l15;
        a[i] = *(const bf8*)&As[row][(((kq << 2) + g) ^ (row & 7)) * 8];
      }
      #pragma unroll
      for (int j = 0; j < 4; ++j){
        int row = wn + j * 16 + l15;
        b[j] = *(const bf8*)&Bs[row][(((kq << 2) + g) ^ (row & 7)) * 8];
      }
      #pragma unroll
      for (int i = 0; i < 4; ++i)
        #pragma unroll
        for (int j = 0; j < 4; ++j)
          acc[i][j] = __builtin_amdgcn_mfma_f32_16x16x32_bf16(a[i], b[j], acc[i][j], 0, 0, 0);
    }
    __syncthreads();
  }
  #pragma unroll
  for (int j = 0; j < 4; ++j){
    int ncol = n0 + wn + j * 16 + l15;
    float bv = bias[ncol];
    #pragma unroll
    for (int i = 0; i < 4; ++i){
      #pragma unroll
      for (int r = 0; r < 4; ++r){
        int m = m0 + wm + i * 16 + g * 4 + r;
        out[(size_t)m * CEMB + ncol] = acc[i][j][r] + bv;
      }
    }
  }
}

extern "C" void kernel_launch(void* const* d_in, const int* in_sizes, int n_in,
                              void* d_out, int out_size, void* d_ws, size_t ws_size,
                              hipStream_t stream){
  const float* x      = (const float*)d_in[0];
  const float* W_attn = (const float*)d_in[1];
  const float* b_attn = (const float*)d_in[2];
  const float* W_o    = (const float*)d_in[3];
  const float* b_o    = (const float*)d_in[4];
  float* out = (float*)d_out;

  char* ws = (char*)d_ws;
  const size_t SZ_T  = (size_t)48 * T * HD * 2;   // 12.58 MB (== X size)
  const size_t SZ_WA = (size_t)N1 * K1 * 2;
  const size_t SZ_WO = (size_t)CEMB * CEMB * 2;
  unsigned short* Xb = (unsigned short*)(ws);
  unsigned short* Vt = (unsigned short*)(ws);     // aliases Xb (dead after gemm_qkv)
  unsigned short* Wa = (unsigned short*)(ws + SZ_T);
  unsigned short* Wo = (unsigned short*)(ws + SZ_T + SZ_WA);
  unsigned short* Qb = (unsigned short*)(ws + SZ_T + SZ_WA + SZ_WO);
  unsigned short* Kb = (unsigned short*)(ws + SZ_T + SZ_WA + SZ_WO + SZ_T);
  unsigned short* Vr = (unsigned short*)(ws + SZ_T + SZ_WA + SZ_WO + 2 * SZ_T);
  unsigned short* Yb = Vr;                        // Vr dead after transpose_v

  cvt_f32_bf16<<<(M1 * K1 / 4 + 255) / 256, 256, 0, stream>>>(x, Xb, M1 * K1 / 4);
  cvt_f32_bf16<<<(N1 * K1 / 4 + 255) / 256, 256, 0, stream>>>(W_attn, Wa, N1 * K1 / 4);
  cvt_f32_bf16<<<(CEMB * CEMB / 4 + 255) / 256, 256, 0, stream>>>(W_o, Wo, CEMB * CEMB / 4);

  gemm_qkv<<<dim3(N1 / 128, M1 / 128), 256, 0, stream>>>(Xb, Wa, b_attn, Qb, Kb, Vr);
  transpose_v<<<dim3(T / 64, 48), 256, 0, stream>>>(Vr, Vt);
  attn<<<dim3(48, 64), 64, 0, stream>>>(Qb, Kb, Vt, Yb);
  gemm_out<<<dim3(CEMB / 128, M1 / 128), 256, 0, stream>>>(Yb, Wo, b_o, out);
}

// Round 8
// 168.895 us; speedup vs baseline: 1.1980x; 1.0278x over previous
//
#include <hip/hip_runtime.h>

#define H 12
#define T 2048
#define HD 64
#define CEMB 768
#define M1 8192   // B*T
#define N1 2304   // 3*C
#define K1 768

typedef __attribute__((ext_vector_type(8))) short bf8;
typedef __attribute__((ext_vector_type(4))) float f4;
typedef __attribute__((ext_vector_type(16))) float f16v;
typedef __attribute__((ext_vector_type(4))) int i4;

__device__ __forceinline__ unsigned short f2bf(float f){
  union { float f; unsigned u; } v; v.f = f;
  unsigned r = v.u + 0x7FFFu + ((v.u >> 16) & 1u);
  return (unsigned short)(r >> 16);
}

__device__ __forceinline__ int cvtpk(float a, float b){
  int r;
  asm("v_cvt_pk_bf16_f32 %0, %1, %2" : "=v"(r) : "v"(a), "v"(b));
  return r;
}

// async global->LDS, 16B per lane; dest = wave-uniform base + lane*16
__device__ __forceinline__ void gload16(const unsigned short* g, unsigned short* l){
  __builtin_amdgcn_global_load_lds((const __attribute__((address_space(1))) void*)g,
                                   (__attribute__((address_space(3))) void*)l, 16, 0, 0);
}

// ---- fused f32->bf16 conversion over x, W_attn, W_o (one launch, 3 ranges) ----
__global__ __launch_bounds__(256) void cvt_all(const float* __restrict__ x,
                                               const float* __restrict__ wa,
                                               const float* __restrict__ wo,
                                               unsigned short* __restrict__ xb,
                                               unsigned short* __restrict__ wab,
                                               unsigned short* __restrict__ wob){
  const int n4x = M1 * K1 / 4, n4a = N1 * K1 / 4, n4o = CEMB * CEMB / 4;
  int i = blockIdx.x * blockDim.x + threadIdx.x;
  const float* in; unsigned short* out; int j;
  if (i < n4x){ in = x; out = xb; j = i; }
  else if (i < n4x + n4a){ in = wa; out = wab; j = i - n4x; }
  else if (i < n4x + n4a + n4o){ in = wo; out = wob; j = i - n4x - n4a; }
  else return;
  float4 v = ((const float4*)in)[j];
  ushort4 o;
  o.x = f2bf(v.x); o.y = f2bf(v.y); o.z = f2bf(v.z); o.w = f2bf(v.w);
  ((ushort4*)out)[j] = o;
}

// ---- QKV projection (m97-style). Q pre-scaled by 0.125*log2(e). V row-major. ----
__global__ __launch_bounds__(256) void gemm_qkv(const unsigned short* __restrict__ A,
                                                const unsigned short* __restrict__ Wb,
                                                const float* __restrict__ bias,
                                                unsigned short* __restrict__ Qb,
                                                unsigned short* __restrict__ Kb,
                                                unsigned short* __restrict__ Vr){
  __shared__ __align__(16) unsigned short As[128][64];
  __shared__ __align__(16) unsigned short Bs[128][64];
  int Lid = blockIdx.x + gridDim.x * blockIdx.y;      // 18*64 = 1152 = 8*144
  int L2 = (Lid & 7) * 144 + (Lid >> 3);
  const int m0 = (L2 / 18) * 128, n0 = (L2 % 18) * 128;
  const int tid = threadIdx.x, w = tid >> 6, lane = tid & 63;
  const int wm = (w >> 1) * 64, wn = (w & 1) * 64;
  const int l15 = lane & 15, g = lane >> 4;
  const int srow = lane >> 3;
  const int scol = ((lane & 7) ^ srow) * 8;
  f4 acc[4][4] = {};
  for (int k0 = 0; k0 < K1; k0 += 64){
    #pragma unroll
    for (int i = 0; i < 4; ++i){
      int rb = i * 32 + w * 8;
      gload16(&A [(size_t)(m0 + rb + srow) * K1 + k0 + scol], &As[rb][0]);
      gload16(&Wb[(size_t)(n0 + rb + srow) * K1 + k0 + scol], &Bs[rb][0]);
    }
    __syncthreads();
    #pragma unroll
    for (int kq = 0; kq < 2; ++kq){
      bf8 a[4], b[4];
      #pragma unroll
      for (int i = 0; i < 4; ++i){
        int row = wm + i * 16 + l15;
        a[i] = *(const bf8*)&As[row][(((kq << 2) + g) ^ (row & 7)) * 8];
      }
      #pragma unroll
      for (int j = 0; j < 4; ++j){
        int row = wn + j * 16 + l15;
        b[j] = *(const bf8*)&Bs[row][(((kq << 2) + g) ^ (row & 7)) * 8];
      }
      #pragma unroll
      for (int i = 0; i < 4; ++i)
        #pragma unroll
        for (int j = 0; j < 4; ++j)
          acc[i][j] = __builtin_amdgcn_mfma_f32_16x16x32_bf16(a[i], b[j], acc[i][j], 0, 0, 0);
    }
    __syncthreads();
  }
  #pragma unroll
  for (int j = 0; j < 4; ++j){
    int ncol = n0 + wn + j * 16 + l15;
    float bv = bias[ncol];
    int which = ncol / CEMB;
    int cc = ncol - which * CEMB;
    int h = cc >> 6, d = cc & 63;
    #pragma unroll
    for (int i = 0; i < 4; ++i){
      #pragma unroll
      for (int r = 0; r < 4; ++r){
        int m = m0 + wm + i * 16 + g * 4 + r;
        int b_ = m >> 11, t = m & 2047;
        size_t idx = ((size_t)(b_ * H + h) * T + t) * HD + d;
        float v = acc[i][j][r] + bv;
        if (which == 0)      Qb[idx] = f2bf(v * 0.18033688f);  // 0.125 * log2(e)
        else if (which == 1) Kb[idx] = f2bf(v);
        else                 Vr[idx] = f2bf(v);
      }
    }
  }
}

// ---- V transpose + kv-quad permute: Vr[bh][t][d] -> Vt[bh][d][perm(t)] ----
__global__ __launch_bounds__(256) void transpose_v(const unsigned short* __restrict__ Vr,
                                                   unsigned short* __restrict__ Vt){
  __shared__ unsigned short Lb[64][66];
  const int bh = blockIdx.y, tt = blockIdx.x;
  const unsigned short* src = Vr + ((size_t)bh * T + tt * 64) * HD;
  unsigned short* dst = Vt + (size_t)bh * HD * T + tt * 64;
  const int tid = threadIdx.x;
  {
    int r = tid >> 2, c = (tid & 3) * 16;
    uint4 v0 = *(const uint4*)&src[r * HD + c];
    uint4 v1 = *(const uint4*)&src[r * HD + c + 8];
    unsigned* lp = (unsigned*)&Lb[r][c];
    lp[0] = v0.x; lp[1] = v0.y; lp[2] = v0.z; lp[3] = v0.w;
    lp[4] = v1.x; lp[5] = v1.y; lp[6] = v1.z; lp[7] = v1.w;
  }
  __syncthreads();
  {
    int d = tid >> 2, tq = tid & 3;
    unsigned ov[8];
    #pragma unroll
    for (int jj = 0; jj < 8; ++jj){
      unsigned lo = Lb[tq * 16 + 2 * jj][d];
      unsigned hi = Lb[tq * 16 + 2 * jj + 1][d];
      ov[jj] = lo | (hi << 16);
    }
    uint4* op = (uint4*)&dst[(size_t)d * T + tq * 16];
    op[0] = make_uint4(ov[0], ov[1], ov[4], ov[5]);   // quads [0,2]
    op[1] = make_uint4(ov[2], ov[3], ov[6], ov[7]);   // quads [1,3]
  }
}

// ---- Flash causal attention v15: R4-passing v11 verbatim + fmax3 max tree ----
// R5-R7's 4-wave shared staging failed 3x (run-varying absmax) despite
// lane-exact index verification; reverted wholesale per pre-commitment.
// Only change vs the R4-passing kernel: the row-max pairwise tree (16-reg
// copy + 15 fmax) is replaced by a v_max3 triplet tree (~7 insts, identical
// result). Staging, sync, softmax numerics, ol row-sum MFMA, epilogue: R4.
__global__ __launch_bounds__(64) void attn(const unsigned short* __restrict__ Qb,
                                           const unsigned short* __restrict__ Kb,
                                           const unsigned short* __restrict__ Vt,
                                           unsigned short* __restrict__ Yb){
  __shared__ __align__(16) unsigned short Ks[2][32][64];
  __shared__ __align__(16) unsigned short Vs[2][64][32];
  const int bh = blockIdx.x;                 // 48 % 8 == 0 -> bh pinned to one XCD
  const int qidx = 63 - (int)blockIdx.y;     // LPT: heavy q-tiles dispatched first
  const int lane = threadIdx.x;
  const int q31 = lane & 31, hi = lane >> 5;
  const int q0 = qidx * 32;
  const unsigned short* Qp = Qb + (size_t)bh * T * HD;
  const unsigned short* Kp = Kb + (size_t)bh * T * HD;
  const unsigned short* Vp = Vt + (size_t)bh * HD * T;
  const int b_ = bh / H, h = bh % H;

  // staging lane constants (pre-swizzled source chunks; LDS dest is linear)
  const int krow = lane >> 3;                         // 0..7 within 8-row slab
  const int kcs  = ((lane & 7) ^ krow) * 8;           // K: chunk ^ (row&7)
  const int vrow = lane >> 2;                         // 0..15 within 16-row slab
  const int vcs  = ((lane & 3) ^ ((lane >> 4) & 3)) * 8;  // V: chunk ^ ((d>>2)&3)

  // Q fragments (B-operand): lane holds Q[q0+q31][ds*16 + hi*8 .. +8]
  bf8 qf[4];
  #pragma unroll
  for (int ds = 0; ds < 4; ++ds)
    qf[ds] = *(const bf8*)&Qp[(q0 + q31) * HD + ds * 16 + hi * 8];

  // all-ones bf16 B operand for the row-sum MFMA
  bf8 ones;
  #pragma unroll
  for (int j = 0; j < 8; ++j) ones[j] = (short)0x3F80;

  f16v o0 = {}, o1 = {}, ol = {};
  float m_i = -1e30f;
  const int ntw = qidx + 1;

  // prologue: stage tile 0 into buf 0
  #pragma unroll
  for (int it = 0; it < 4; ++it)
    gload16(&Kp[(size_t)(it * 8 + krow) * HD + kcs], &Ks[0][it * 8][0]);
  #pragma unroll
  for (int it = 0; it < 4; ++it)
    gload16(&Vp[(size_t)(it * 16 + vrow) * T + vcs], &Vs[0][it * 16][0]);

  #pragma unroll 2
  for (int t = 0; t < ntw; ++t){
    const int cur = t & 1;
    const int kv0 = t * 32;
    if (t + 1 < ntw){     // stage next tile into other buffer, then counted wait
      const int nkv = kv0 + 32;
      #pragma unroll
      for (int it = 0; it < 4; ++it)
        gload16(&Kp[(size_t)(nkv + it * 8 + krow) * HD + kcs], &Ks[cur ^ 1][it * 8][0]);
      #pragma unroll
      for (int it = 0; it < 4; ++it)
        gload16(&Vp[(size_t)(it * 16 + vrow) * T + nkv + vcs], &Vs[cur ^ 1][it * 16][0]);
      asm volatile("s_waitcnt vmcnt(8)" ::: "memory");
    } else {
      asm volatile("s_waitcnt vmcnt(0)" ::: "memory");
    }
    __builtin_amdgcn_sched_barrier(0);

    // ---- QK^T (swapped): s[kv][q]; K from LDS (XOR-swizzled read)
    f16v s0 = {};
    __builtin_amdgcn_s_setprio(1);
    #pragma unroll
    for (int ds = 0; ds < 4; ++ds){
      bf8 k0 = *(const bf8*)&Ks[cur][q31][(((2 * ds + hi)) ^ (q31 & 7)) * 8];
      s0 = __builtin_amdgcn_mfma_f32_32x32x16_bf16(k0, qf[ds], s0, 0, 0, 0);
    }
    __builtin_amdgcn_s_setprio(0);
    if (t == ntw - 1){    // diagonal tile: causal mask
      #pragma unroll
      for (int r = 0; r < 16; ++r){
        int kvr = kv0 + (r & 3) + 8 * (r >> 2) + 4 * hi;
        if (kvr > q0 + q31) s0[r] = -1e30f;
      }
    }
    // ---- row max: v_max3 triplet tree (identical result, ~7 insts vs ~32)
    float a0 = fmaxf(fmaxf(s0[0], s0[1]), s0[2]);
    float a1 = fmaxf(fmaxf(s0[3], s0[4]), s0[5]);
    float a2 = fmaxf(fmaxf(s0[6], s0[7]), s0[8]);
    float a3 = fmaxf(fmaxf(s0[9], s0[10]), s0[11]);
    float a4 = fmaxf(fmaxf(s0[12], s0[13]), s0[14]);
    float mx = fmaxf(fmaxf(fmaxf(a0, a1), a2), fmaxf(fmaxf(a3, a4), s0[15]));
    mx = fmaxf(mx, __shfl_xor(mx, 32));
    // ---- defer-max: rescale only when max grew by > 8 (log2 domain);
    //      scale redistributed via shfl (row f(r,hi) held by lane q31==row)
    if (__any(mx > m_i + 8.f)){
      float mn = fmaxf(m_i, mx);
      float sc_ = __builtin_exp2f(m_i - mn);
      #pragma unroll
      for (int r = 0; r < 16; ++r){
        float s = __shfl(sc_, (r & 3) + 8 * (r >> 2) + 4 * hi);
        o0[r] *= s; o1[r] *= s; ol[r] *= s;
      }
      m_i = mn;
    }
    // ---- p = exp2(s - m) in place
    #pragma unroll
    for (int r = 0; r < 16; ++r) s0[r] = __builtin_exp2f(s0[r] - m_i);
    // ---- PV + row-sum: A = in-lane pack of own p regs; V^T from LDS;
    //      l accumulated by all-ones MFMA on the matrix pipe
    union { i4 i; bf8 h; } pa;
    __builtin_amdgcn_s_setprio(1);
    #pragma unroll
    for (int ks = 0; ks < 2; ++ks){
      const int off = ks * 8;
      pa.i = (i4){ cvtpk(s0[off], s0[off+1]), cvtpk(s0[off+2], s0[off+3]),
                   cvtpk(s0[off+4], s0[off+5]), cvtpk(s0[off+6], s0[off+7]) };
      bf8 v0 = *(const bf8*)&Vs[cur][q31]     [((2 * ks + hi) ^ ((q31 >> 2) & 3)) * 8];
      bf8 v1 = *(const bf8*)&Vs[cur][32 + q31][((2 * ks + hi) ^ ((q31 >> 2) & 3)) * 8];
      o0 = __builtin_amdgcn_mfma_f32_32x32x16_bf16(pa.h, v0, o0, 0, 0, 0);
      o1 = __builtin_amdgcn_mfma_f32_32x32x16_bf16(pa.h, v1, o1, 0, 0, 0);
      ol = __builtin_amdgcn_mfma_f32_32x32x16_bf16(pa.h, ones, ol, 0, 0, 0);
    }
    __builtin_amdgcn_s_setprio(0);
  }

  // ---- epilogue: per-register exact 1/l, store Y (bf16); no LDS, no cross-lane
  #pragma unroll
  for (int r = 0; r < 16; ++r){
    int qrow = q0 + (r & 3) + 8 * (r >> 2) + 4 * hi;
    float inv = 1.0f / ol[r];
    size_t base = ((size_t)b_ * T + qrow) * CEMB + h * HD;
    Yb[base + q31]      = f2bf(o0[r] * inv);
    Yb[base + 32 + q31] = f2bf(o1[r] * inv);
  }
}

// ---- Output projection (m97 structure), fp32 out ----
__global__ __launch_bounds__(256) void gemm_out(const unsigned short* __restrict__ A,
                                                const unsigned short* __restrict__ Wb,
                                                const float* __restrict__ bias,
                                                float* __restrict__ out){
  __shared__ __align__(16) unsigned short As[128][64];
  __shared__ __align__(16) unsigned short Bs[128][64];
  int Lid = blockIdx.x + gridDim.x * blockIdx.y;      // 6*64 = 384 = 8*48
  int L2 = (Lid & 7) * 48 + (Lid >> 3);
  const int m0 = (L2 / 6) * 128, n0 = (L2 % 6) * 128;
  const int tid = threadIdx.x, w = tid >> 6, lane = tid & 63;
  const int wm = (w >> 1) * 64, wn = (w & 1) * 64;
  const int l15 = lane & 15, g = lane >> 4;
  const int srow = lane >> 3;
  const int scol = ((lane & 7) ^ srow) * 8;
  f4 acc[4][4] = {};
  for (int k0 = 0; k0 < CEMB; k0 += 64){
    #pragma unroll
    for (int i = 0; i < 4; ++i){
      int rb = i * 32 + w * 8;
      gload16(&A [(size_t)(m0 + rb + srow) * CEMB + k0 + scol], &As[rb][0]);
      gload16(&Wb[(size_t)(n0 + rb + srow) * CEMB + k0 + scol], &Bs[rb][0]);
    }
    __syncthreads();
    #pragma unroll
    for (int kq = 0; kq < 2; ++kq){
      bf8 a[4], b[4];
      #pragma unroll
      for (int i = 0; i < 4; ++i){
        int row = wm + i * 16 + l15;
        a[i] = *(const bf8*)&As[row][(((kq << 2) + g) ^ (row & 7)) * 8];
      }
      #pragma unroll
      for (int j = 0; j < 4; ++j){
        int row = wn + j * 16 + l15;
        b[j] = *(const bf8*)&Bs[row][(((kq << 2) + g) ^ (row & 7)) * 8];
      }
      #pragma unroll
      for (int i = 0; i < 4; ++i)
        #pragma unroll
        for (int j = 0; j < 4; ++j)
          acc[i][j] = __builtin_amdgcn_mfma_f32_16x16x32_bf16(a[i], b[j], acc[i][j], 0, 0, 0);
    }
    __syncthreads();
  }
  #pragma unroll
  for (int j = 0; j < 4; ++j){
    int ncol = n0 + wn + j * 16 + l15;
    float bv = bias[ncol];
    #pragma unroll
    for (int i = 0; i < 4; ++i){
      #pragma unroll
      for (int r = 0; r < 4; ++r){
        int m = m0 + wm + i * 16 + g * 4 + r;
        out[(size_t)m * CEMB + ncol] = acc[i][j][r] + bv;
      }
    }
  }
}

extern "C" void kernel_launch(void* const* d_in, const int* in_sizes, int n_in,
                              void* d_out, int out_size, void* d_ws, size_t ws_size,
                              hipStream_t stream){
  const float* x      = (const float*)d_in[0];
  const float* W_attn = (const float*)d_in[1];
  const float* b_attn = (const float*)d_in[2];
  const float* W_o    = (const float*)d_in[3];
  const float* b_o    = (const float*)d_in[4];
  float* out = (float*)d_out;

  char* ws = (char*)d_ws;
  const size_t SZ_T  = (size_t)48 * T * HD * 2;   // 12.58 MB (== X size)
  const size_t SZ_WA = (size_t)N1 * K1 * 2;
  const size_t SZ_WO = (size_t)CEMB * CEMB * 2;
  unsigned short* Xb = (unsigned short*)(ws);
  unsigned short* Vt = (unsigned short*)(ws);     // aliases Xb (dead after gemm_qkv)
  unsigned short* Wa = (unsigned short*)(ws + SZ_T);
  unsigned short* Wo = (unsigned short*)(ws + SZ_T + SZ_WA);
  unsigned short* Qb = (unsigned short*)(ws + SZ_T + SZ_WA + SZ_WO);
  unsigned short* Kb = (unsigned short*)(ws + SZ_T + SZ_WA + SZ_WO + SZ_T);
  unsigned short* Vr = (unsigned short*)(ws + SZ_T + SZ_WA + SZ_WO + 2 * SZ_T);
  unsigned short* Yb = Vr;                        // Vr dead after transpose_v

  const int n4tot = (M1 * K1 + N1 * K1 + CEMB * CEMB) / 4;
  cvt_all<<<(n4tot + 255) / 256, 256, 0, stream>>>(x, W_attn, W_o, Xb, Wa, Wo);

  gemm_qkv<<<dim3(N1 / 128, M1 / 128), 256, 0, stream>>>(Xb, Wa, b_attn, Qb, Kb, Vr);
  transpose_v<<<dim3(T / 64, 48), 256, 0, stream>>>(Vr, Vt);
  attn<<<dim3(48, 64), 64, 0, stream>>>(Qb, Kb, Vt, Yb);
  gemm_out<<<dim3(CEMB / 128, M1 / 128), 256, 0, stream>>>(Yb, Wo, b_o, out);
}